// Round 10
// baseline (219.760 us; speedup 1.0000x reference)
//
#include <hip/hip_runtime.h>
#include <math.h>

#define HIDDEN 64
#define SEQ 128
#define BATCH 64
#define NPTS (BATCH * SEQ)   // 8192
#define TMAXV 20.0f
#define L2E 1.4426950408889634f
#define LN2 0.6931471805599453f

typedef float v2f __attribute__((ext_vector_type(2)));

__device__ __forceinline__ float fexp2(float x) { return __builtin_amdgcn_exp2f(x); }
__device__ __forceinline__ float flog2(float x) { return __builtin_amdgcn_logf(x); }
__device__ __forceinline__ float frcp(float x)  { return __builtin_amdgcn_rcpf(x); }
__device__ __forceinline__ float fsigmoid(float x) { return frcp(1.0f + fexp2(-x * L2E)); }
__device__ __forceinline__ float ftanh(float x)    { return 1.0f - 2.0f * frcp(1.0f + fexp2(2.0f * x * L2E)); }

// ---- DPP wave64 sum: VALU-pipe cross-lane (no LDS round trips). Result uniform.
template <int CTRL>
__device__ __forceinline__ float dpp_mov(float x) {
    int r = __builtin_amdgcn_update_dpp(0, __float_as_int(x), CTRL, 0xf, 0xf, false);
    return __int_as_float(r);
}
__device__ __forceinline__ float wave_sum_dpp(float x) {
    x += dpp_mov<0x111>(x);   // row_shr:1
    x += dpp_mov<0x112>(x);   // row_shr:2
    x += dpp_mov<0x114>(x);   // row_shr:4
    x += dpp_mov<0x118>(x);   // row_shr:8  -> lane 16r+15 = row sum
    x += dpp_mov<0x142>(x);   // row_bcast:15
    x += dpp_mov<0x143>(x);   // row_bcast:31 -> lane 63 = total
    return __int_as_float(__builtin_amdgcn_readlane(__float_as_int(x), 63));
}

__device__ __forceinline__ float wave_sum_shfl(float v) {
    v += __shfl_xor(v, 1);  v += __shfl_xor(v, 2);  v += __shfl_xor(v, 4);
    v += __shfl_xor(v, 8);  v += __shfl_xor(v, 16); v += __shfl_xor(v, 32);
    return v;
}

// Blocks [0,64): LSTM rollout, ONE WAVE per batch (64 threads). Lane h owns all
// 4 gate rows {h,64+h,128+h,192+h} -> gates are LANE-LOCAL: no act exchange, no
// barrier. Weights made register-resident (256 VGPRs) via the r9-proven
// mechanism: global->LDS stage, lgkmcnt+memory-clobber (kills store-to-load
// forwarding), readback, then a PER-ITERATION memory clobber makes any in-loop
// reload illegal -> values must stay in VGPRs (budget 512, launch_bounds(64,1)).
// r3/r5/r6/r9 established delivery isn't the wall; the serial chain is. This
// structure has the shortest chain: hx LDS round-trip (overlapped by the sigma
// DPP chain) + 128 pk_fma issue + lane-local cell update.
// Blocks [64,576): expert-expert MMD, one wave each (same per-wave partial sums
// as the 256-thread version: identical contiguous-64 point groups + xor order).
__global__ __launch_bounds__(64, 1) void gen_and_ee(
    const float* __restrict__ upool,   // [B,S]
    const float* __restrict__ texp,    // [B,S]
    const float* __restrict__ Wih,     // [256]
    const float* __restrict__ Whh,     // [256,64]
    const float* __restrict__ bih,     // [256]
    const float* __restrict__ bhh,     // [256]
    const float* __restrict__ Vw,      // [64]
    const float* __restrict__ Vb,      // [1]
    float* __restrict__ tl,            // [NPTS] workspace
    float* __restrict__ out)           // [1] loss accumulator
{
    // [0,16384) floats: weight stage (64 chunks x 64 lanes x float4) [LSTM]
    //                   hx_s aliases floats [0,64); qbuf aliases (EE)
    // [16384,16512): lu_s[128]
    __shared__ __align__(16) float smem[16520];

    const int bid = blockIdx.x;
    const int tid = threadIdx.x;      // 0..63

    if (bid < BATCH) {
        const int h = tid;
        float* hx_s = smem;           // [64], aliases stage chunk (g0,k0)
        float* lu_s = smem + 16384;

        // ---- stage all 4 gate rows into LDS: [gate*16+k][lane] float4 ----
        float4* st = (float4*)smem;
        {
            const float4* r0 = (const float4*)(Whh + (h)       * 64);
            const float4* r1 = (const float4*)(Whh + (64 + h)  * 64);
            const float4* r2 = (const float4*)(Whh + (128 + h) * 64);
            const float4* r3 = (const float4*)(Whh + (192 + h) * 64);
            #pragma unroll
            for (int k = 0; k < 16; ++k) {
                st[(k)      * 64 + h] = r0[k];
                st[(16 + k) * 64 + h] = r1[k];
                st[(32 + k) * 64 + h] = r2[k];
                st[(48 + k) * 64 + h] = r3[k];
            }
        }
        // publish + kill store-to-load forwarding (single wave: no s_barrier needed)
        asm volatile("s_waitcnt lgkmcnt(0)" ::: "memory");

        // ---- readback to 256 VGPRs ----
        v2f wi[32], wf[32], wg[32], wo[32];
        #pragma unroll
        for (int k = 0; k < 16; ++k) {
            float4 v0 = st[(k)      * 64 + h];
            float4 v1 = st[(16 + k) * 64 + h];
            float4 v2_ = st[(32 + k) * 64 + h];
            float4 v3 = st[(48 + k) * 64 + h];
            wi[2*k] = (v2f){v0.x, v0.y}; wi[2*k+1] = (v2f){v0.z, v0.w};
            wf[2*k] = (v2f){v1.x, v1.y}; wf[2*k+1] = (v2f){v1.z, v1.w};
            wg[2*k] = (v2f){v2_.x, v2_.y}; wg[2*k+1] = (v2f){v2_.z, v2_.w};
            wo[2*k] = (v2f){v3.x, v3.y}; wo[2*k+1] = (v2f){v3.z, v3.w};
        }
        asm volatile("" ::: "memory");   // readback complete before any hx write

        const float bi_ = bih[h]       + bhh[h];
        const float bf_ = bih[64 + h]  + bhh[64 + h];
        const float bg_ = bih[128 + h] + bhh[128 + h];
        const float bo_ = bih[192 + h] + bhh[192 + h];
        const float wii = Wih[h], wif = Wih[64 + h], wig = Wih[128 + h], wio = Wih[192 + h];
        const float vw = Vw[h];
        const float vb = Vb[0];

        lu_s[h]      = -flog2(upool[bid * SEQ + h]) * LN2;
        lu_s[64 + h] = -flog2(upool[bid * SEQ + 64 + h]) * LN2;
        hx_s[h] = 0.0f;
        float cx = 0.0f;

        // step 0: hx = 0 -> sigma = elu(Vb)+1 (uniform)
        float sg0 = (vb > 0.0f) ? (vb + 1.0f) : fexp2(vb * L2E);
        float cum = lu_s[0] * frcp(sg0);
        float keep0 = (h == 0) ? cum : 0.0f;
        float keep1 = 0.0f;

        #pragma unroll 1
        for (int s = 0; s < SEQ - 1; ++s) {
            float lunext = lu_s[s + 1];
            const float4* h4 = (const float4*)hx_s;   // broadcast b128 reads
            // accumulation order bit-identical to r1/r2 (harness-verified)
            v2f i0={0.f,0.f}, i1={0.f,0.f}, i2={0.f,0.f}, i3={0.f,0.f};
            v2f f0={0.f,0.f}, f1={0.f,0.f}, f2={0.f,0.f}, f3={0.f,0.f};
            v2f g0={0.f,0.f}, g1={0.f,0.f}, g2={0.f,0.f}, g3={0.f,0.f};
            v2f o0={0.f,0.f}, o1={0.f,0.f}, o2={0.f,0.f}, o3={0.f,0.f};
            #pragma unroll
            for (int k = 0; k < 16; k += 2) {
                float4 va4 = h4[k];
                float4 vb4 = h4[k + 1];
                v2f x0 = (v2f){va4.x, va4.y};
                v2f x1 = (v2f){va4.z, va4.w};
                v2f x2 = (v2f){vb4.x, vb4.y};
                v2f x3 = (v2f){vb4.z, vb4.w};
                i0 += wi[2*k] * x0; i1 += wi[2*k+1] * x1; i2 += wi[2*k+2] * x2; i3 += wi[2*k+3] * x3;
                f0 += wf[2*k] * x0; f1 += wf[2*k+1] * x1; f2 += wf[2*k+2] * x2; f3 += wf[2*k+3] * x3;
                g0 += wg[2*k] * x0; g1 += wg[2*k+1] * x1; g2 += wg[2*k+2] * x2; g3 += wg[2*k+3] * x3;
                o0 += wo[2*k] * x0; o1 += wo[2*k+1] * x1; o2 += wo[2*k+2] * x2; o3 += wo[2*k+3] * x3;
            }
            v2f ia = (i0 + i1) + (i2 + i3);
            v2f fa = (f0 + f1) + (f2 + f3);
            v2f ga = (g0 + g1) + (g2 + g3);
            v2f oa = (o0 + o1) + (o2 + o3);
            float gi = (ia.x + ia.y) + bi_ + cum * wii;
            float gf = (fa.x + fa.y) + bf_ + cum * wif;
            float gg = (ga.x + ga.y) + bg_ + cum * wig;
            float go = (oa.x + oa.y) + bo_ + cum * wio;

            float ig = fsigmoid(gi);
            float fg = fsigmoid(gf);
            float gt = ftanh(gg);
            float og = fsigmoid(go);
            cx = fg * cx + ig * gt;
            float hx = og * ftanh(cx);
            hx_s[h] = hx;                          // in-wave lgkmcnt ordering only
            // per-iteration clobber: any reload of staged weights after this
            // point is illegal -> wi/wf/wg/wo must remain register-resident
            asm volatile("" ::: "memory");

            float tot = wave_sum_dpp(hx * vw);     // overlaps hx LDS round-trip
            float xx  = tot + vb;
            float sg  = (xx > 0.0f) ? (xx + 1.0f) : fexp2(xx * L2E);
            cum += lunext * frcp(sg);

            const int sp = s + 1;
            keep0 = (h == sp) ? cum : keep0;       // sp>=64 never matches h<64
            keep1 = (h == sp - 64) ? cum : keep1;  // sp<64 -> negative, no match
        }
        tl[bid * SEQ + h]      = keep0;
        tl[bid * SEQ + 64 + h] = keep1;
    } else {
        // ---------------- expert-expert MMD term (one wave per block) --------
        const int eb = bid - BATCH;      // 0..511
        const int pc = eb & 127;         // p-chunk (64 points)
        const int qs = eb >> 7;          // q-split (2048 points)

        float2* qbuf = (float2*)smem;    // [2048], aliases stage pool

        const int p = pc * 64 + tid;
        const float tp = texp[p];
        const float mp = (tp < TMAXV && tp > 0.0f) ? 1.0f : 0.0f;

        const int q0 = qs * 2048;
        for (int i = tid; i < 2048; i += 64) {
            float tq = texp[q0 + i];
            float mq = (tq < TMAXV && tq > 0.0f) ? 1.0f : 0.0f;
            qbuf[i] = make_float2(tq, mq);
        }
        __syncthreads();

        float acc = 0.0f;
        #pragma unroll 4
        for (int i = 0; i < 2048; ++i) {
            float2 qq = qbuf[i];
            float d = tp - qq.x;
            acc = fmaf(qq.y, fexp2(d * d * (-L2E)), acc);
        }
        acc *= mp;
        acc = wave_sum_shfl(acc);        // same xor order as before -> same wave sums
        if (tid == 0) atomicAdd(out, acc);
    }
}

// ll + le terms. Grid (32, 16): 32 p-chunks of 256 x 16 q-splits of 512.
__global__ __launch_bounds__(256) void ll_le(
    const float* __restrict__ texp,
    const float* __restrict__ tl,
    float* __restrict__ out)
{
    __shared__ __align__(16) float4 qbuf[512];
    __shared__ float red[4];

    const int pc = blockIdx.x;
    const int qs = blockIdx.y;
    const int tid = threadIdx.x;

    const int p = pc * 256 + tid;
    const float tlp = tl[p];
    const float mlp = (tlp < TMAXV && tlp > 0.0f) ? 1.0f : 0.0f;

    const int q0 = qs * 512;
    for (int i = tid; i < 512; i += 256) {
        float tq = tl[q0 + i];
        float mq = (tq < TMAXV && tq > 0.0f) ? 1.0f : 0.0f;
        float te = texp[q0 + i];
        float me = (te < TMAXV && te > 0.0f) ? 1.0f : 0.0f;
        qbuf[i] = make_float4(tq, mq, te, me);
    }
    __syncthreads();

    float val = 0.0f;
    // learner times are cumsum of Exp(1) increments: most p-points exceed T_MAX;
    // fully-masked waves skip the whole q-loop (wave-uniform branch).
    if (__ballot(mlp != 0.0f) != 0ULL) {
        float a_ll = 0.0f, a_le = 0.0f;
        #pragma unroll 4
        for (int i = 0; i < 512; ++i) {
            float4 q = qbuf[i];
            float d1 = tlp - q.x;
            a_ll = fmaf(q.y, fexp2(d1 * d1 * (-L2E)), a_ll);
            float d2 = tlp - q.z;
            a_le = fmaf(q.w, fexp2(d2 * d2 * (-L2E)), a_le);
        }
        val = mlp * (a_ll - 2.0f * a_le);
    }

    val = wave_sum_shfl(val);
    if ((tid & 63) == 0) red[tid >> 6] = val;
    __syncthreads();
    if (tid == 0) atomicAdd(out, red[0] + red[1] + red[2] + red[3]);
}

extern "C" void kernel_launch(void* const* d_in, const int* in_sizes, int n_in,
                              void* d_out, int out_size, void* d_ws, size_t ws_size,
                              hipStream_t stream) {
    const float* upool = (const float*)d_in[0];
    const float* texp  = (const float*)d_in[1];
    const float* Wih   = (const float*)d_in[2];
    const float* Whh   = (const float*)d_in[3];
    const float* bih   = (const float*)d_in[4];
    const float* bhh   = (const float*)d_in[5];
    const float* Vw    = (const float*)d_in[6];
    const float* Vb    = (const float*)d_in[7];
    float* out = (float*)d_out;
    float* tl  = (float*)d_ws;   // 8192 floats = 32 KB

    hipMemsetAsync(out, 0, sizeof(float), stream);
    hipLaunchKernelGGL(gen_and_ee, dim3(BATCH + 512), dim3(64), 0, stream,
                       upool, texp, Wih, Whh, bih, bhh, Vw, Vb, tl, out);
    hipLaunchKernelGGL(ll_le, dim3(32, 16), dim3(256), 0, stream, texp, tl, out);
}